// Round 1
// baseline (182.778 us; speedup 1.0000x reference)
//
#include <hip/hip_runtime.h>

#define PP     16
#define LRDIM  256
#define DDIM   1024
#define LN_EPS 1e-5f

// ---------------------------------------------------------------------------
// K0: transpose W_up [D][LR] -> Wt [LR][D] so the table3 GEMM reads coalesced.
// ---------------------------------------------------------------------------
__global__ __launch_bounds__(256) void k_transpose_w(const float* __restrict__ W,
                                                     float* __restrict__ Wt) {
    __shared__ float tile[32][33];
    const int bx = blockIdx.x;          // LR/32 = 8
    const int by = blockIdx.y;          // D/32 = 32
    const int tx = threadIdx.x & 31;
    const int ty = threadIdx.x >> 5;    // 0..7
#pragma unroll
    for (int k = 0; k < 4; ++k) {
        int d = by * 32 + ty + k * 8;
        int j = bx * 32 + tx;
        tile[ty + k * 8][tx] = W[d * LRDIM + j];
    }
    __syncthreads();
#pragma unroll
    for (int k = 0; k < 4; ++k) {
        int j = bx * 32 + ty + k * 8;
        int d = by * 32 + tx;
        Wt[j * DDIM + d] = tile[tx][ty + k * 8];
    }
}

// ---------------------------------------------------------------------------
// K1a: table2[p][c][j] = sum_i pos_emb[p][i][j] * byte_table[c][i]
// block = 256 threads (one j each); each block does 4 consecutive c for one p
// so each pos_emb element load is reused 4x.
// grid = 16 * 64
// ---------------------------------------------------------------------------
__global__ __launch_bounds__(256) void k_table2(const float* __restrict__ bt,
                                                const float* __restrict__ pe,
                                                float* __restrict__ t2) {
    const int p  = blockIdx.x >> 6;          // 0..15
    const int c0 = (blockIdx.x & 63) * 4;    // 0..252
    const int j  = threadIdx.x;
    const float* pep = pe + (size_t)p * LRDIM * LRDIM;
    float a0 = 0.f, a1 = 0.f, a2 = 0.f, a3 = 0.f;
    for (int i = 0; i < LRDIM; ++i) {
        float v = pep[i * LRDIM + j];        // coalesced across j
        a0 += v * bt[(c0 + 0) * LRDIM + i];  // uniform -> scalar loads
        a1 += v * bt[(c0 + 1) * LRDIM + i];
        a2 += v * bt[(c0 + 2) * LRDIM + i];
        a3 += v * bt[(c0 + 3) * LRDIM + i];
    }
    t2[(size_t)((p * 256) + c0 + 0) * LRDIM + j] = a0;
    t2[(size_t)((p * 256) + c0 + 1) * LRDIM + j] = a1;
    t2[(size_t)((p * 256) + c0 + 2) * LRDIM + j] = a2;
    t2[(size_t)((p * 256) + c0 + 3) * LRDIM + j] = a3;
}

// ---------------------------------------------------------------------------
// K1b: table3[p][c][d] = sum_j table2[p][c][j] * Wt[j][d]
// block = 256 threads; fixed (p, group of 8 c); thread t owns 4 consecutive d
// (d = 4t..4t+3) -> float4 loads of Wt rows. table2 rows staged in LDS.
// grid = 16 * 32
// ---------------------------------------------------------------------------
__global__ __launch_bounds__(256) void k_table3(const float* __restrict__ t2,
                                                const float* __restrict__ Wt,
                                                float* __restrict__ t3) {
    const int p  = blockIdx.x >> 5;          // 0..15
    const int c0 = (blockIdx.x & 31) * 8;    // 0..248
    const int t  = threadIdx.x;

    __shared__ float s2[8][LRDIM];
#pragma unroll
    for (int r = 0; r < 8; ++r)
        s2[r][t] = t2[(size_t)((p * 256) + c0 + r) * LRDIM + t];
    __syncthreads();

    float4 acc[8];
#pragma unroll
    for (int r = 0; r < 8; ++r) acc[r] = make_float4(0.f, 0.f, 0.f, 0.f);

    const float4* wt4 = (const float4*)Wt;
#pragma unroll 4
    for (int j = 0; j < LRDIM; ++j) {
        float4 w = wt4[(size_t)j * (DDIM / 4) + t];   // coalesced 16B/lane
#pragma unroll
        for (int r = 0; r < 8; ++r) {
            float a = s2[r][j];                        // LDS broadcast
            acc[r].x += a * w.x;
            acc[r].y += a * w.y;
            acc[r].z += a * w.z;
            acc[r].w += a * w.w;
        }
    }

#pragma unroll
    for (int r = 0; r < 8; ++r) {
        ((float4*)t3)[(size_t)((p * 256) + c0 + r) * (DDIM / 4) + t] = acc[r];
    }
}

// ---------------------------------------------------------------------------
// K2: per-token gather-sum + bias + LayerNorm. One wave (64 lanes) per token,
// each lane owns 16 d-values as 4x float4 (d = 4*(q*64+lane) .. +3).
// ---------------------------------------------------------------------------
__global__ __launch_bounds__(256) void k_tokens(const int* __restrict__ ids,
                                                const float* __restrict__ t3,
                                                const float* __restrict__ b_up,
                                                const float* __restrict__ gamma,
                                                const float* __restrict__ beta,
                                                float* __restrict__ out,
                                                int ntok) {
    const int gtid = blockIdx.x * blockDim.x + threadIdx.x;
    const int wid  = gtid >> 6;          // token index
    const int lane = threadIdx.x & 63;
    if (wid >= ntok) return;

    const int* myids = ids + (size_t)wid * PP;

    float4 acc[4];
#pragma unroll
    for (int q = 0; q < 4; ++q) acc[q] = make_float4(0.f, 0.f, 0.f, 0.f);

    for (int p = 0; p < PP; ++p) {
        const int id = myids[p];         // same addr across wave -> broadcast
        if (id < 0) continue;
        const float4* row = (const float4*)(t3 + (size_t)(p * 256 + id) * DDIM);
#pragma unroll
        for (int q = 0; q < 4; ++q) {
            float4 v = row[q * 64 + lane];
            acc[q].x += v.x; acc[q].y += v.y; acc[q].z += v.z; acc[q].w += v.w;
        }
    }

    // + b_up, accumulate sum / sumsq for LN
    float s = 0.f, ss = 0.f;
#pragma unroll
    for (int q = 0; q < 4; ++q) {
        float4 b = ((const float4*)b_up)[q * 64 + lane];
        acc[q].x += b.x; acc[q].y += b.y; acc[q].z += b.z; acc[q].w += b.w;
        s  += acc[q].x + acc[q].y + acc[q].z + acc[q].w;
        ss += acc[q].x * acc[q].x + acc[q].y * acc[q].y +
              acc[q].z * acc[q].z + acc[q].w * acc[q].w;
    }
#pragma unroll
    for (int off = 32; off > 0; off >>= 1) {
        s  += __shfl_xor(s, off);
        ss += __shfl_xor(ss, off);
    }
    const float mu  = s * (1.f / DDIM);
    const float var = ss * (1.f / DDIM) - mu * mu;
    const float inv = rsqrtf(var + LN_EPS);

#pragma unroll
    for (int q = 0; q < 4; ++q) {
        const int idx = q * 64 + lane;
        float4 g  = ((const float4*)gamma)[idx];
        float4 be = ((const float4*)beta)[idx];
        float4 o;
        o.x = (acc[q].x - mu) * inv * g.x + be.x;
        o.y = (acc[q].y - mu) * inv * g.y + be.y;
        o.z = (acc[q].z - mu) * inv * g.z + be.z;
        o.w = (acc[q].w - mu) * inv * g.w + be.w;
        ((float4*)out)[(size_t)wid * (DDIM / 4) + idx] = o;
    }
}

// ---------------------------------------------------------------------------
extern "C" void kernel_launch(void* const* d_in, const int* in_sizes, int n_in,
                              void* d_out, int out_size, void* d_ws, size_t ws_size,
                              hipStream_t stream) {
    const int*   ids   = (const int*)  d_in[0];
    const float* bt    = (const float*)d_in[1];
    const float* pe    = (const float*)d_in[2];
    const float* W     = (const float*)d_in[3];
    const float* b_up  = (const float*)d_in[4];
    const float* gamma = (const float*)d_in[5];
    const float* beta  = (const float*)d_in[6];
    float* out = (float*)d_out;

    const int ntok = in_sizes[0] / PP;   // B*S

    char* ws = (char*)d_ws;
    float* Wt = (float*)(ws);                  // LR*D*4   = 1 MB
    float* t2 = (float*)(ws + (1 << 20));      // P*256*LR*4 = 4 MB
    float* t3 = (float*)(ws + (5 << 20));      // P*256*D*4  = 16 MB

    hipLaunchKernelGGL(k_transpose_w, dim3(8, 32), dim3(256), 0, stream, W, Wt);
    hipLaunchKernelGGL(k_table2, dim3(16 * 64), dim3(256), 0, stream, bt, pe, t2);
    hipLaunchKernelGGL(k_table3, dim3(16 * 32), dim3(256), 0, stream, t2, Wt, t3);
    hipLaunchKernelGGL(k_tokens, dim3((ntok + 3) / 4), dim3(256), 0, stream,
                       ids, t3, b_up, gamma, beta, out, ntok);
}

// Round 2
// 79.578 us; speedup vs baseline: 2.2968x; 2.2968x over previous
//
#include <hip/hip_runtime.h>
#include <stdint.h>

#define PP     16
#define LRDIM  256
#define DDIM   1024
#define LN_EPS 1e-5f

typedef __attribute__((ext_vector_type(8))) short  short8;
typedef __attribute__((ext_vector_type(4))) float  f32x4;

__device__ __forceinline__ uint32_t bf16_rne(float f) {
    uint32_t u = __builtin_bit_cast(uint32_t, f);
    return (u + 0x7fffu + ((u >> 16) & 1u)) >> 16;
}
__device__ __forceinline__ float bf_lo(uint32_t u) {
    return __builtin_bit_cast(float, u << 16);
}
__device__ __forceinline__ float bf_hi(uint32_t u) {
    return __builtin_bit_cast(float, u & 0xffff0000u);
}

// ---------------------------------------------------------------------------
// K1: table2b[p][c][j] = bf16( sum_i pos_emb[p][i][j] * byte_table[c][i] )
// 2 MB bf16 table -> L2-resident everywhere.
// ---------------------------------------------------------------------------
__global__ __launch_bounds__(256) void k_table2b(const float* __restrict__ bt,
                                                 const float* __restrict__ pe,
                                                 unsigned short* __restrict__ t2b) {
    const int p  = blockIdx.x >> 6;          // 0..15
    const int c0 = (blockIdx.x & 63) * 4;    // 0..252
    const int j  = threadIdx.x;
    const float* pep = pe + (size_t)p * LRDIM * LRDIM;
    float a0 = 0.f, a1 = 0.f, a2 = 0.f, a3 = 0.f;
    for (int i = 0; i < LRDIM; ++i) {
        float v = pep[i * LRDIM + j];        // coalesced across j
        a0 += v * bt[(c0 + 0) * LRDIM + i];  // uniform -> scalar loads
        a1 += v * bt[(c0 + 1) * LRDIM + i];
        a2 += v * bt[(c0 + 2) * LRDIM + i];
        a3 += v * bt[(c0 + 3) * LRDIM + i];
    }
    t2b[(size_t)((p * 256) + c0 + 0) * LRDIM + j] = (unsigned short)bf16_rne(a0);
    t2b[(size_t)((p * 256) + c0 + 1) * LRDIM + j] = (unsigned short)bf16_rne(a1);
    t2b[(size_t)((p * 256) + c0 + 2) * LRDIM + j] = (unsigned short)bf16_rne(a2);
    t2b[(size_t)((p * 256) + c0 + 3) * LRDIM + j] = (unsigned short)bf16_rne(a3);
}

// ---------------------------------------------------------------------------
// K2: repack W_up [D][LR] f32 -> bf16 in MFMA B-fragment order:
// wb[(nfg*8 + ks)*64 + lane] = 8 bf16 of W_up[nfg*16 + (lane&15)]
//                                        [ks*32 + (lane>>4)*8 + 0..7]
// so k_main's B-frag load is a single coalesced uint4 per lane.
// ---------------------------------------------------------------------------
__global__ __launch_bounds__(256) void k_wblk(const float* __restrict__ W,
                                              uint4* __restrict__ wb) {
    const int gt  = blockIdx.x * 256 + threadIdx.x;   // 0..32767
    const int l   = gt & 63;
    const int ks  = (gt >> 6) & 7;
    const int nfg = gt >> 9;                          // 0..63
    const int n   = nfg * 16 + (l & 15);
    const int k   = ks * 32 + (l >> 4) * 8;
    const float* src = W + (size_t)n * LRDIM + k;
    uint32_t r[4];
#pragma unroll
    for (int q = 0; q < 4; ++q) {
        uint32_t lo = bf16_rne(src[2 * q + 0]);
        uint32_t hi = bf16_rne(src[2 * q + 1]);
        r[q] = lo | (hi << 16);
    }
    wb[gt] = make_uint4(r[0], r[1], r[2], r[3]);
}

// ---------------------------------------------------------------------------
// K3: fused gather-sum (A-tile, 32 tokens x LR) -> MFMA GEMM (K=256, N=1024)
//     -> bias -> LayerNorm -> out. Block = 256 threads (4 waves), wave w owns
//     N-slice [w*256, w*256+256). A-tile in XOR-swizzled LDS bf16.
// ---------------------------------------------------------------------------
__global__ __launch_bounds__(256, 2) void k_main(const int* __restrict__ ids,
                                                 const unsigned short* __restrict__ t2b,
                                                 const uint4* __restrict__ wb,
                                                 const float* __restrict__ b_up,
                                                 const float* __restrict__ gamma,
                                                 const float* __restrict__ beta,
                                                 float* __restrict__ out,
                                                 int ntok) {
    __shared__ __align__(16) unsigned char As[32 * 512];   // 16 KB bf16 A tile
    __shared__ float ln_s[4][32];
    __shared__ float ln_ss[4][32];
    __shared__ int   ids_s[32 * PP];

    const int t    = threadIdx.x;
    const int tok0 = blockIdx.x * 32;
    const int w    = t >> 6;        // wave 0..3
    const int l    = t & 63;        // lane
    const int lo4  = l & 15;
    const int hi2  = l >> 4;        // 0..3

    // ---- ids tile ----
    for (int i = t; i < 32 * PP; i += 256) {
        int tok = tok0 + (i >> 4);
        ids_s[i] = (tok < ntok) ? ids[(size_t)tok0 * PP + i] : -1;
    }
    __syncthreads();

    // ---- stage: wave w gathers tokens w*8 .. w*8+7; lane owns lr = l*4..+3 ----
    float av[8][4];
#pragma unroll
    for (int tt = 0; tt < 8; ++tt)
#pragma unroll
        for (int e = 0; e < 4; ++e) av[tt][e] = 0.f;

#pragma unroll
    for (int tt = 0; tt < 8; ++tt) {
        const int tl = (w << 3) + tt;
#pragma unroll 4
        for (int p = 0; p < PP; ++p) {
            const int id = ids_s[tl * PP + p];
            const float msk = (id >= 0) ? 1.f : 0.f;
            const int id2 = id & 255;
            const uint2 vv = *(const uint2*)(t2b + ((size_t)((p << 8) + id2) * LRDIM) + (l << 2));
            av[tt][0] = fmaf(msk, bf_lo(vv.x), av[tt][0]);
            av[tt][1] = fmaf(msk, bf_hi(vv.x), av[tt][1]);
            av[tt][2] = fmaf(msk, bf_lo(vv.y), av[tt][2]);
            av[tt][3] = fmaf(msk, bf_hi(vv.y), av[tt][3]);
        }
    }

    // pack -> swizzled LDS (byte ^= (row&7)<<4, preserves 8B alignment)
#pragma unroll
    for (int tt = 0; tt < 8; ++tt) {
        const int row = (w << 3) + tt;
        uint2 pk;
        pk.x = bf16_rne(av[tt][0]) | (bf16_rne(av[tt][1]) << 16);
        pk.y = bf16_rne(av[tt][2]) | (bf16_rne(av[tt][3]) << 16);
        const int byte = (l << 3) ^ ((row & 7) << 4);
        *(uint2*)(As + (row << 9) + byte) = pk;
    }
    __syncthreads();

    // ---- MFMA: acc[m2][nf] over K=256 in 8 k-steps ----
    f32x4 acc[2][16];
#pragma unroll
    for (int m2 = 0; m2 < 2; ++m2)
#pragma unroll
        for (int nf = 0; nf < 16; ++nf) {
            f32x4 z = {0.f, 0.f, 0.f, 0.f};
            acc[m2][nf] = z;
        }

#pragma unroll
    for (int ks = 0; ks < 8; ++ks) {
        short8 af[2];
#pragma unroll
        for (int m2 = 0; m2 < 2; ++m2) {
            const int row  = m2 * 16 + lo4;
            const int byte = (ks * 64 + hi2 * 16) ^ ((row & 7) << 4);
            af[m2] = *(const short8*)(As + (row << 9) + byte);
        }
#pragma unroll
        for (int nf = 0; nf < 16; ++nf) {
            const int nfg = (w << 4) + nf;
            const uint4 bv = wb[(size_t)(nfg * 8 + ks) * 64 + l];
            const short8 bf = __builtin_bit_cast(short8, bv);
            acc[0][nf] = __builtin_amdgcn_mfma_f32_16x16x32_bf16(af[0], bf, acc[0][nf], 0, 0, 0);
            acc[1][nf] = __builtin_amdgcn_mfma_f32_16x16x32_bf16(af[1], bf, acc[1][nf], 0, 0, 0);
        }
    }

    // ---- epilogue: +bias, per-token stats (token slot q = m2*4 + r) ----
    float s_[8], ss_[8];
#pragma unroll
    for (int q = 0; q < 8; ++q) { s_[q] = 0.f; ss_[q] = 0.f; }

#pragma unroll
    for (int nf = 0; nf < 16; ++nf) {
        const int col = (w << 8) + (nf << 4) + lo4;
        const float bu = b_up[col];
#pragma unroll
        for (int m2 = 0; m2 < 2; ++m2) {
            f32x4 v = acc[m2][nf];
            v.x += bu; v.y += bu; v.z += bu; v.w += bu;
            acc[m2][nf] = v;
            const int q0 = m2 * 4;
            s_[q0 + 0] += v.x; ss_[q0 + 0] += v.x * v.x;
            s_[q0 + 1] += v.y; ss_[q0 + 1] += v.y * v.y;
            s_[q0 + 2] += v.z; ss_[q0 + 2] += v.z * v.z;
            s_[q0 + 3] += v.w; ss_[q0 + 3] += v.w * v.w;
        }
    }
    // reduce across the 16 lanes (lo4) that share each token
#pragma unroll
    for (int off = 1; off < 16; off <<= 1)
#pragma unroll
        for (int q = 0; q < 8; ++q) {
            s_[q]  += __shfl_xor(s_[q], off);
            ss_[q] += __shfl_xor(ss_[q], off);
        }
    if (lo4 == 0) {
#pragma unroll
        for (int q = 0; q < 8; ++q) {
            const int tl = (q >> 2) * 16 + hi2 * 4 + (q & 3);
            ln_s[w][tl]  = s_[q];
            ln_ss[w][tl] = ss_[q];
        }
    }
    __syncthreads();

    float mu_[8], inv_[8];
#pragma unroll
    for (int q = 0; q < 8; ++q) {
        const int tl = (q >> 2) * 16 + hi2 * 4 + (q & 3);
        const float S  = ln_s[0][tl] + ln_s[1][tl] + ln_s[2][tl] + ln_s[3][tl];
        const float SS = ln_ss[0][tl] + ln_ss[1][tl] + ln_ss[2][tl] + ln_ss[3][tl];
        const float mu  = S * (1.f / DDIM);
        const float var = SS * (1.f / DDIM) - mu * mu;
        mu_[q]  = mu;
        inv_[q] = rsqrtf(var + LN_EPS);
    }

    // ---- write out ----
#pragma unroll
    for (int nf = 0; nf < 16; ++nf) {
        const int col = (w << 8) + (nf << 4) + lo4;
        const float g  = gamma[col];
        const float bb = beta[col];
#pragma unroll
        for (int m2 = 0; m2 < 2; ++m2) {
            const f32x4 v = acc[m2][nf];
#pragma unroll
            for (int r = 0; r < 4; ++r) {
                const int q   = m2 * 4 + r;
                const int tl  = m2 * 16 + hi2 * 4 + r;
                const int tok = tok0 + tl;
                if (tok < ntok)
                    out[(size_t)tok * DDIM + col] = (v[r] - mu_[q]) * inv_[q] * g + bb;
            }
        }
    }
}

// ---------------------------------------------------------------------------
extern "C" void kernel_launch(void* const* d_in, const int* in_sizes, int n_in,
                              void* d_out, int out_size, void* d_ws, size_t ws_size,
                              hipStream_t stream) {
    const int*   ids   = (const int*)  d_in[0];
    const float* bt    = (const float*)d_in[1];
    const float* pe    = (const float*)d_in[2];
    const float* W     = (const float*)d_in[3];
    const float* b_up  = (const float*)d_in[4];
    const float* gamma = (const float*)d_in[5];
    const float* beta  = (const float*)d_in[6];
    float* out = (float*)d_out;

    const int ntok = in_sizes[0] / PP;   // B*S = 16384

    char* ws = (char*)d_ws;
    unsigned short* t2b = (unsigned short*)(ws);        // 16*256*256*2 = 2 MB
    uint4*          wbb = (uint4*)(ws + (2 << 20));     // 64*8*64*16   = 512 KB

    hipLaunchKernelGGL(k_table2b, dim3(16 * 64), dim3(256), 0, stream, bt, pe, t2b);
    hipLaunchKernelGGL(k_wblk, dim3(128), dim3(256), 0, stream, W, wbb);
    hipLaunchKernelGGL(k_main, dim3((ntok + 31) / 32), dim3(256), 0, stream,
                       ids, t2b, wbb, b_up, gamma, beta, out, ntok);
}